// Round 8
// baseline (6256.408 us; speedup 1.0000x reference)
//
#include <hip/hip_runtime.h>
#include <hip/hip_bf16.h>
#include <hip/hip_fp16.h>

#define BB   4
#define NN   16384
#define MM   1024
#define CC   256
#define KK   32
#define O1   128
#define FF   512
#define LTOT (BB*MM*KK)   // 131072
#define NSLOT 64
#define CH   16384
#define NCH2 (LTOT/CH)    // 8

__device__ __forceinline__ float bf2f(unsigned short u){
    return __uint_as_float(((unsigned int)u) << 16);
}
__device__ __forceinline__ float anyf(const void* p, size_t i, int f){
    if (f == 1) return bf2f(((const unsigned short*)p)[i]);
    if (f == 2) return __half2float(((const __half*)p)[i]);
    return ((const float*)p)[i];
}

// ---- dtype detector: 0=f32, 1=bf16, 2=fp16 ----
__global__ void k_det(const unsigned short* __restrict__ u, int n, int* __restrict__ flag){
    if (threadIdx.x != 0 || blockIdx.x != 0) return;
    int W = n < 64 ? n : 64;
    bool allz = true;
    for (int k = 0; k < W; k++) if (u[k]){ allz = false; break; }
    if (allz){ *flag = 1; return; }
    if (u[0] == 0x3F80u){ *flag = 1; return; }      // bf16 1.0
    if (u[0] == 0x3C00u){ *flag = 2; return; }      // fp16 1.0
    if (W >= 2){
        unsigned int f0 = ((unsigned int)u[1] << 16) | u[0];
        if (__uint_as_float(f0) == 1.0f){ *flag = 0; return; }  // f32 1.0
    }
    int ce = 0, co = 0, ne = 0, no_ = 0;
    for (int k = 0; k < W; k++){
        unsigned short x = u[k];
        float v = fabsf(bf2f(x));
        int sane = (x == 0) || (v >= 0.0009765625f && v <= 64.f);
        if (k & 1){ no_++; co += sane; } else { ne++; ce += sane; }
    }
    if (ce * 4 >= ne * 3){ *flag = 1; return; }
    if (co * 4 >= no_ * 3 && ce * 5 < ne * 2){ *flag = 0; return; }
    *flag = 2;
}

__global__ __launch_bounds__(256) void k_cvtf(const void* __restrict__ src,
                                              float* __restrict__ dst, int n,
                                              const int* __restrict__ flag){
    int t = blockIdx.x * 256 + threadIdx.x;
    if (t >= n) return;
    dst[t] = anyf(src, t, *flag);
}

// ---------------- Stage 1 ----------------
__global__ __launch_bounds__(256) void k_mlp1(const float* __restrict__ sw1,
                                              const float* __restrict__ feat,
                                              float* __restrict__ h1,
                                              float* __restrict__ stats1){
    int t = blockIdx.x * 256 + threadIdx.x;
    int m = t & (MM - 1);
    int o = (t >> 10) & (O1 - 1);
    int b = t >> 17;
    const float* fb = feat + (size_t)b * CC * MM + m;
    const float* w  = sw1 + o * CC;
    float acc = 0.f;
    #pragma unroll 8
    for (int c = 0; c < CC; c++) acc += w[c] * fb[(size_t)c * MM];
    h1[t] = acc;
    float s = acc, s2 = acc * acc;
    for (int off = 32; off; off >>= 1){ s += __shfl_down(s, off); s2 += __shfl_down(s2, off); }
    __shared__ float ls[8];
    int lane = threadIdx.x & 63, wid = threadIdx.x >> 6;
    if (lane == 0){ ls[wid] = s; ls[4 + wid] = s2; }
    __syncthreads();
    if (threadIdx.x == 0){
        atomicAdd(&stats1[2*o],   ls[0]+ls[1]+ls[2]+ls[3]);
        atomicAdd(&stats1[2*o+1], ls[4]+ls[5]+ls[6]+ls[7]);
    }
}

// ---------------- Stage 2 ----------------
__global__ __launch_bounds__(256) void k_bn1mlp2(const float* __restrict__ h1,
                                                 const float* __restrict__ stats1,
                                                 const float* __restrict__ sg1,
                                                 const float* __restrict__ sb1,
                                                 const float* __restrict__ sw2,
                                                 float* __restrict__ h2,
                                                 float* __restrict__ stats2){
    __shared__ float sc[O1], bi[O1];
    int tid = threadIdx.x;
    if (tid < O1){
        const float invn = 1.f / (BB * MM);
        float mean = stats1[2*tid] * invn;
        float var  = fmaxf(stats1[2*tid+1] * invn - mean * mean, 0.f);
        float rs   = 1.f / sqrtf(var + 1e-5f);
        float s    = rs * sg1[tid];
        float b_   = sb1[tid] - mean * s;
        if (!isfinite(s) || !isfinite(b_)){ s = 1.f; b_ = 0.f; }
        sc[tid] = s; bi[tid] = b_;
    }
    __syncthreads();
    int t = blockIdx.x * 256 + tid;
    int m = t & (MM - 1);
    int r = t >> 10; int o2 = r % 3; int b = r / 3;
    const float* hb = h1 + (size_t)b * O1 * MM + m;
    const float* w  = sw2 + o2 * O1;
    float acc = 0.f;
    #pragma unroll 8
    for (int c = 0; c < O1; c++){
        float v = hb[(size_t)c * MM] * sc[c] + bi[c];
        v = v > 0.f ? v : 0.f;
        acc += w[c] * v;
    }
    h2[t] = acc;
    float s = acc, s2 = acc * acc;
    for (int off = 32; off; off >>= 1){ s += __shfl_down(s, off); s2 += __shfl_down(s2, off); }
    __shared__ float ls[8];
    int lane = tid & 63, wid = tid >> 6;
    if (lane == 0){ ls[wid] = s; ls[4 + wid] = s2; }
    __syncthreads();
    if (tid == 0){
        atomicAdd(&stats2[2*o2],   ls[0]+ls[1]+ls[2]+ls[3]);
        atomicAdd(&stats2[2*o2+1], ls[4]+ls[5]+ls[6]+ls[7]);
    }
}

__global__ void k_fin2(const float* __restrict__ stats2, const float* __restrict__ sg2,
                       const float* __restrict__ sb2, float* __restrict__ scb2){
    int t = threadIdx.x;
    if (t < 3){
        const float invn = 1.f / (BB * MM);
        float mean = stats2[2*t] * invn;
        float var  = fmaxf(stats2[2*t+1] * invn - mean * mean, 0.f);
        float rs   = 1.f / sqrtf(var + 1e-5f);
        float s    = rs * sg2[t];
        float b    = sb2[t] - mean * s;
        if (!isfinite(s) || !isfinite(b)){ s = 1.f; b = 0.f; }
        scb2[t] = s; scb2[4 + t] = b;
    }
}

// ---------------- ball query ----------------
__global__ __launch_bounds__(256) void k_ballq(const float* __restrict__ fxyz,
                                               const float* __restrict__ h2,
                                               const float* __restrict__ scb2,
                                               const float* __restrict__ bxyz,
                                               float* __restrict__ nxyz,
                                               int* __restrict__ idxbuf){
    int q    = blockIdx.x * 4 + (threadIdx.x >> 6);
    int lane = threadIdx.x & 63;
    int b = q >> 10, m = q & (MM - 1);
    float nx[3];
    #pragma unroll
    for (int c = 0; c < 3; c++){
        float v = h2[((size_t)b * 3 + c) * MM + m] * scb2[c] + scb2[4 + c];
        v = v > 0.f ? v : 0.f;
        nx[c] = fxyz[(size_t)q * 3 + c] + v;
    }
    if (lane == 0){
        nxyz[q*3+0] = nx[0]; nxyz[q*3+1] = nx[1]; nxyz[q*3+2] = nx[2];
    }
    const float* bx = bxyz + (size_t)b * NN * 3;
    int have = 0, firstj = 0;
    int* out = idxbuf + (size_t)q * KK;
    for (int j0 = 0; j0 < NN && have < KK; j0 += 64){
        int j = j0 + lane;
        float dx = bx[j*3+0] - nx[0];
        float dy = bx[j*3+1] - nx[1];
        float dz = bx[j*3+2] - nx[2];
        float d2 = dx*dx + dy*dy + dz*dz;
        bool pred = d2 < 1.0f;
        unsigned long long mask = __ballot(pred);
        if (mask){
            if (have == 0) firstj = j0 + (__ffsll((unsigned long long)mask) - 1);
            if (pred){
                int rank = __popcll(mask & ((1ull << lane) - 1ull));
                int pos = have + rank;
                if (pos < KK) out[pos] = j;
            }
            have += (int)__popcll(mask);
        }
    }
    if (have < KK){
        int fill = (have > 0) ? firstj : 0;
        for (int p = have + lane; p < KK; p += 64) out[p] = fill;
    }
}

// ---------------- idx2 / xyzdiff ----------------
__global__ __launch_bounds__(256) void k_xyzd(const int* __restrict__ idxbuf,
                                              const float* __restrict__ bxyz,
                                              const float* __restrict__ nxyz,
                                              int* __restrict__ idx2,
                                              float4* __restrict__ xyzd){
    int l = blockIdx.x * 256 + threadIdx.x;
    int b = l >> 15;
    int q = l >> 5;
    int j = idxbuf[l];
    idx2[l] = b * NN + j;
    const float* p = bxyz + ((size_t)b * NN + j) * 3;
    xyzd[l] = make_float4(p[0] - nxyz[q*3+0], p[1] - nxyz[q*3+1], p[2] - nxyz[q*3+2], 0.f);
}

// ---------------- transpose (B,C,N) -> (B,N,C) f32, flag-aware ----------------
__global__ __launch_bounds__(256) void k_transp(const void* __restrict__ bfv,
                                                const int* __restrict__ flag,
                                                float* __restrict__ ft){
    __shared__ float tile[32][33];
    int f = *flag;
    int bid = blockIdx.x;
    int nt = bid & 511;
    int ct = (bid >> 9) & 7;
    int b  = bid >> 12;
    int tx = threadIdx.x & 31, ty = threadIdx.x >> 5;
    size_t base = ((size_t)b * CC + ct * 32) * NN + nt * 32;
    #pragma unroll
    for (int r = 0; r < 32; r += 8)
        tile[ty + r][tx] = anyf(bfv, base + (size_t)(ty + r) * NN + tx, f);
    __syncthreads();
    float* dst = ft + ((size_t)b * NN + nt * 32) * CC + ct * 32;
    #pragma unroll
    for (int r = 0; r < 32; r += 8) dst[(size_t)(ty + r) * CC + tx] = tile[tx][ty + r];
}

// ---------------- weight prep ----------------
__global__ void k_wprep(const float* __restrict__ w1, float* __restrict__ w1p,
                        float4* __restrict__ w1xp){
    int t = blockIdx.x * 256 + threadIdx.x;
    int o = t >> 8, c = t & 255;
    w1p[t] = w1[o * 259 + 3 + c];
    if (t < 512) w1xp[t] = make_float4(w1[t*259], w1[t*259+1], w1[t*259+2], 0.f);
}

// ---------------- GEMM ----------------
__global__ __launch_bounds__(256) void k_gemm(const float* __restrict__ A,
                                              const float* __restrict__ X,
                                              int Cs,
                                              const float* __restrict__ scb,
                                              float* __restrict__ Y,
                                              double* __restrict__ stats){
    __shared__ float As[16][64];
    __shared__ float Xs[16][68];
    __shared__ float lsc[FF], lbi[FF];
    int tid = threadIdx.x;
    if (scb){
        for (int c = tid; c < Cs; c += 256){ lsc[c] = scb[c]; lbi[c] = scb[Cs + c]; }
    }
    int bid = blockIdx.x;
    int ot = bid & 7;
    int lt = bid >> 3;
    int o0 = ot * 64, l0 = lt * 64;
    int tx = tid & 15, ty = tid >> 4;
    int la = tid & 63;
    int ca4 = (tid >> 6) * 4;
    float acc[4][4] = {};
    __syncthreads();
    for (int c0 = 0; c0 < Cs; c0 += 16){
        float4 av = *(const float4*)(A + (size_t)(o0 + la) * Cs + c0 + ca4);
        float4 xv = *(const float4*)(X + (size_t)(l0 + la) * Cs + c0 + ca4);
        if (scb){
            xv.x = fmaxf(xv.x * lsc[c0+ca4+0] + lbi[c0+ca4+0], 0.f);
            xv.y = fmaxf(xv.y * lsc[c0+ca4+1] + lbi[c0+ca4+1], 0.f);
            xv.z = fmaxf(xv.z * lsc[c0+ca4+2] + lbi[c0+ca4+2], 0.f);
            xv.w = fmaxf(xv.w * lsc[c0+ca4+3] + lbi[c0+ca4+3], 0.f);
        }
        __syncthreads();
        As[ca4+0][la] = av.x; As[ca4+1][la] = av.y; As[ca4+2][la] = av.z; As[ca4+3][la] = av.w;
        Xs[ca4+0][la] = xv.x; Xs[ca4+1][la] = xv.y; Xs[ca4+2][la] = xv.z; Xs[ca4+3][la] = xv.w;
        __syncthreads();
        #pragma unroll
        for (int cc = 0; cc < 16; cc++){
            float a0 = As[cc][ty*4+0], a1 = As[cc][ty*4+1], a2 = As[cc][ty*4+2], a3 = As[cc][ty*4+3];
            float b0 = Xs[cc][tx*4+0], b1 = Xs[cc][tx*4+1], b2 = Xs[cc][tx*4+2], b3 = Xs[cc][tx*4+3];
            acc[0][0] += a0*b0; acc[0][1] += a0*b1; acc[0][2] += a0*b2; acc[0][3] += a0*b3;
            acc[1][0] += a1*b0; acc[1][1] += a1*b1; acc[1][2] += a1*b2; acc[1][3] += a1*b3;
            acc[2][0] += a2*b0; acc[2][1] += a2*b1; acc[2][2] += a2*b2; acc[2][3] += a2*b3;
            acc[3][0] += a3*b0; acc[3][1] += a3*b1; acc[3][2] += a3*b2; acc[3][3] += a3*b3;
        }
    }
    if (Y){
        #pragma unroll
        for (int j = 0; j < 4; j++){
            float4 v = make_float4(acc[0][j], acc[1][j], acc[2][j], acc[3][j]);
            *(float4*)(Y + (size_t)(l0 + tx*4 + j) * FF + o0 + ty*4) = v;
        }
    }
    if (stats){
        float s1[4] = {0,0,0,0}, s2[4] = {0,0,0,0};
        #pragma unroll
        for (int j = 0; j < 4; j++){
            #pragma unroll
            for (int i = 0; i < 4; i++){ s1[i] += acc[i][j]; s2[i] += acc[i][j]*acc[i][j]; }
        }
        #pragma unroll
        for (int off = 8; off; off >>= 1){
            #pragma unroll
            for (int i = 0; i < 4; i++){ s1[i] += __shfl_down(s1[i], off, 16); s2[i] += __shfl_down(s2[i], off, 16); }
        }
        if (tx == 0){
            int slot = bid & (NSLOT - 1);
            double* sp = stats + ((size_t)slot * FF + o0 + ty*4) * 2;
            #pragma unroll
            for (int i = 0; i < 4; i++){
                atomicAdd(&sp[2*i],   (double)s1[i]);
                atomicAdd(&sp[2*i+1], (double)s2[i]);
            }
        }
    }
}

// ---------------- finalize BN ----------------
__global__ void k_finL(const double* __restrict__ stats, const float* __restrict__ g,
                       const float* __restrict__ bt, float* __restrict__ scb){
    int o = blockIdx.x * 256 + threadIdx.x;
    double s = 0.0, s2 = 0.0;
    for (int k = 0; k < NSLOT; k++){
        s  += stats[((size_t)k * FF + o) * 2];
        s2 += stats[((size_t)k * FF + o) * 2 + 1];
    }
    double mean = s / (double)LTOT;
    double var  = s2 / (double)LTOT - mean * mean;
    if (!(var > 0.0)) var = 0.0;
    double rs = 1.0 / sqrt(var + 1e-5);
    double sc = rs * (double)g[o];
    double bi = (double)bt[o] - mean * sc;
    float scf = (float)sc, bif = (float)bi;
    if (!isfinite(scf) || !isfinite(bif)){ scf = 1.f; bif = 0.f; }
    scb[o] = scf;
    scb[FF + o] = bif;
}

// ---------------- y1 stats ----------------
__global__ __launch_bounds__(256) void k_y1stats(const float* __restrict__ z,
                                                 const int* __restrict__ idx2,
                                                 const float4* __restrict__ xyzd,
                                                 const float4* __restrict__ w1xp,
                                                 double* __restrict__ stats){
    int tid = threadIdx.x, bid = blockIdx.x;
    int o1 = tid, o2 = tid + 256;
    float4 wa = w1xp[o1], wb = w1xp[o2];
    double s1a=0, s2a=0, s1b=0, s2b=0;
    for (int p = 0; p < LTOT/2048; p++){
        int l = bid + p * 2048;
        int r = idx2[l];
        float4 d = xyzd[l];
        const float* zr = z + (size_t)r * FF;
        float ya = zr[o1] + d.x*wa.x + d.y*wa.y + d.z*wa.z;
        float yb = zr[o2] + d.x*wb.x + d.y*wb.y + d.z*wb.z;
        s1a += ya; s2a += (double)ya*ya;
        s1b += yb; s2b += (double)yb*yb;
    }
    int slot = bid & (NSLOT - 1);
    double* sp = stats + (size_t)slot * FF * 2;
    atomicAdd(&sp[2*o1],   s1a); atomicAdd(&sp[2*o1+1], s2a);
    atomicAdd(&sp[2*o2],   s1b); atomicAdd(&sp[2*o2+1], s2b);
}

// ---------------- materialize X1 chunk ----------------
__global__ __launch_bounds__(256) void k_y1mat(const float* __restrict__ z,
                                               const int* __restrict__ idx2,
                                               const float4* __restrict__ xyzd,
                                               const float4* __restrict__ w1xp,
                                               const float* __restrict__ scb,
                                               float* __restrict__ t1, int L0){
    int tid = threadIdx.x, bid = blockIdx.x;
    int o1 = tid, o2 = tid + 256;
    float4 wa = w1xp[o1], wb = w1xp[o2];
    float sa = scb[o1], ba = scb[FF+o1], sb = scb[o2], bb = scb[FF+o2];
    for (int p = 0; p < CH/1024; p++){
        int ll = bid + p * 1024;
        int l  = L0 + ll;
        int r = idx2[l];
        float4 d = xyzd[l];
        const float* zr = z + (size_t)r * FF;
        float ya = zr[o1] + d.x*wa.x + d.y*wa.y + d.z*wa.z;
        float yb = zr[o2] + d.x*wb.x + d.y*wb.y + d.z*wb.z;
        t1[(size_t)ll * FF + o1] = fmaxf(ya * sa + ba, 0.f);
        t1[(size_t)ll * FF + o2] = fmaxf(yb * sb + bb, 0.f);
    }
}

// ---------------- final max: out[q,o] = max_k relu(bn3(y3)) — FLOAT32 OUTPUT ----------------
__global__ __launch_bounds__(256) void k_maxout(const float* __restrict__ y3,
                                                const float* __restrict__ scb,
                                                float* __restrict__ out,
                                                int q0){
    int qr = blockIdx.x;
    int q = q0 + qr;
    int o = threadIdx.x;
    const float* yb = y3 + (size_t)qr * KK * FF;
    #pragma unroll
    for (int rep = 0; rep < 2; rep++, o += 256){
        float sc = scb[o], bi = scb[FF + o];
        float mx = 0.f;
        for (int k = 0; k < KK; k++){
            float v = fmaxf(yb[(size_t)k * FF + o] * sc + bi, 0.f);
            mx = fmaxf(mx, v);
        }
        out[(size_t)q * FF + o] = mx;
    }
}

// ---------------- stage diagnostics (float sentinel, fires only on unhealthy) ----------------
__global__ __launch_bounds__(256) void k_diag(const float* __restrict__ ff,
                                              const float* __restrict__ w1f,
                                              const float* __restrict__ featT,
                                              const float* __restrict__ z,
                                              const float* __restrict__ xyzdf,
                                              const float* __restrict__ scb1,
                                              const float* __restrict__ scbL2,
                                              const float* __restrict__ scbL3,
                                              const float* __restrict__ y3,
                                              float* __restrict__ out){
    __shared__ float red[4];
    int tid = threadIdx.x;
    int bad = 0, isn = 0;
    const float* arr[9] = {ff, w1f, featT, z, xyzdf, scb1, scbL2, scbL3, y3};
    const int   len[9] = {4096, 4096, 8192, 8192, 4096, 1024, 1024, 1024, 8192};
    for (int k = 0; k < 9; k++){
        float s = 0.f;
        const float* a = arr[k];
        for (int i = tid; i < len[k]; i += 256) s += fabsf(a[i]);
        for (int off = 32; off; off >>= 1) s += __shfl_down(s, off);
        if ((tid & 63) == 0) red[tid >> 6] = s;
        __syncthreads();
        float t = red[0] + red[1] + red[2] + red[3];
        __syncthreads();
        if (bad == 0 && !(t > 1e-6f && t < 1e15f)){
            bad = k + 1;
            isn = isfinite(t) ? 0 : 1;
        }
    }
    if (tid == 0 && bad) out[0] = 512.f * bad + 256.f * isn;
}

extern "C" void kernel_launch(void* const* d_in, const int* in_sizes, int n_in,
                              void* d_out, int out_size, void* d_ws, size_t ws_size,
                              hipStream_t stream) {
    static const int NSZ[19] = {12288, 1048576, 196608, 16777216, 32768, 128, 128,
                                384, 3, 3, 132608, 512, 512, 262144, 512, 512,
                                262144, 512, 512};
    float* out = (float*)d_out;   // OUTPUT IS FLOAT32 (reference returns jnp.float32)

    char* w = (char*)d_ws;
    size_t off = 0;
    auto take = [&](size_t bytes)->size_t{
        size_t r = off; off += (bytes + 255) & ~(size_t)255; return r;
    };
    size_t o_stats1  = take(256 * 4);
    size_t o_stats2  = take(8 * 4);
    size_t o_statsA  = take((size_t)NSLOT * FF * 2 * 8);
    size_t o_statsL2 = take((size_t)NSLOT * FF * 2 * 8);
    size_t o_statsL3 = take((size_t)NSLOT * FF * 2 * 8);
    size_t zero_end  = off;
    size_t o_flags   = take(19 * 4);
    size_t o_cv[19];
    for (int i = 0; i < 19; i++){
        if (i == 3){ o_cv[i] = 0; continue; }
        o_cv[i] = take((size_t)NSZ[i] * 4);
    }
    size_t o_scb2    = take(8 * 4);
    size_t o_scb1    = take(FF * 2 * 4);
    size_t o_scbL2   = take(FF * 2 * 4);
    size_t o_scbL3   = take(FF * 2 * 4);
    size_t o_h1      = take((size_t)BB * O1 * MM * 4);
    size_t o_h2      = take((size_t)BB * 3 * MM * 4);
    size_t o_nxyz    = take((size_t)BB * MM * 3 * 4);
    size_t o_idx     = take((size_t)LTOT * 4);
    size_t o_idx2    = take((size_t)LTOT * 4);
    size_t o_xyzd    = take((size_t)LTOT * 16);
    size_t o_w1p     = take((size_t)FF * CC * 4);
    size_t o_w1xp    = take((size_t)FF * 16);
    size_t o_featT   = take((size_t)BB * NN * CC * 4);
    size_t o_t1      = o_featT;
    size_t o_t2      = o_featT + (size_t)CH * FF * 4;
    size_t o_z       = take((size_t)BB * NN * FF * 4);
    (void)ws_size; (void)n_in; (void)in_sizes; (void)out_size;

    float*  stats1  = (float*) (w + o_stats1);
    float*  stats2  = (float*) (w + o_stats2);
    double* statsA  = (double*)(w + o_statsA);
    double* statsL2 = (double*)(w + o_statsL2);
    double* statsL3 = (double*)(w + o_statsL3);
    int*    flags   = (int*)   (w + o_flags);
    float*  scb2    = (float*) (w + o_scb2);
    float*  scb1    = (float*) (w + o_scb1);
    float*  scbL2   = (float*) (w + o_scbL2);
    float*  scbL3   = (float*) (w + o_scbL3);
    float*  h1      = (float*) (w + o_h1);
    float*  h2      = (float*) (w + o_h2);
    float*  nxyz    = (float*) (w + o_nxyz);
    int*    idxbuf  = (int*)   (w + o_idx);
    int*    idx2    = (int*)   (w + o_idx2);
    float4* xyzd    = (float4*)(w + o_xyzd);
    float*  w1p     = (float*) (w + o_w1p);
    float4* w1xp    = (float4*)(w + o_w1xp);
    float*  featT   = (float*) (w + o_featT);
    float*  t1      = (float*) (w + o_t1);
    float*  t2      = (float*) (w + o_t2);
    float*  z       = (float*) (w + o_z);

    hipMemsetAsync(w, 0, zero_end, stream);

    float* cv[19];
    for (int i = 0; i < 19; i++){
        k_det<<<1, 64, 0, stream>>>((const unsigned short*)d_in[i], NSZ[i], flags + i);
        if (i == 3){ cv[i] = nullptr; continue; }
        cv[i] = (float*)(w + o_cv[i]);
    }
    for (int i = 0; i < 19; i++){
        if (i == 3) continue;
        k_cvtf<<<(NSZ[i] + 255) / 256, 256, 0, stream>>>(d_in[i], cv[i], NSZ[i], flags + i);
    }
    float* fx = cv[0], *ffp = cv[1], *bx = cv[2];
    float* sw1f = cv[4], *sg1f = cv[5], *sb1f = cv[6];
    float* sw2f = cv[7], *sg2f = cv[8], *sb2f = cv[9];
    float* w1f = cv[10], *g1f = cv[11], *b1f = cv[12];
    float* w2f = cv[13], *g2f = cv[14], *b2f = cv[15];
    float* w3f = cv[16], *g3f = cv[17], *b3f = cv[18];

    k_mlp1   <<<2048, 256, 0, stream>>>(sw1f, ffp, h1, stats1);
    k_bn1mlp2<<<48,   256, 0, stream>>>(h1, stats1, sg1f, sb1f, sw2f, h2, stats2);
    k_fin2   <<<1,    64,  0, stream>>>(stats2, sg2f, sb2f, scb2);
    k_ballq  <<<BB*MM/4, 256, 0, stream>>>(fx, h2, scb2, bx, nxyz, idxbuf);
    k_xyzd   <<<LTOT/256, 256, 0, stream>>>(idxbuf, bx, nxyz, idx2, xyzd);
    k_transp <<<BB*(CC/32)*(NN/32), 256, 0, stream>>>(d_in[3], flags + 3, featT);
    k_wprep  <<<512, 256, 0, stream>>>(w1f, w1p, w1xp);

    k_gemm <<<8 * (BB*NN/64), 256, 0, stream>>>(w1p, featT, CC, nullptr, z, nullptr);

    k_y1stats<<<2048, 256, 0, stream>>>(z, idx2, xyzd, w1xp, statsA);
    k_finL  <<<2, 256, 0, stream>>>(statsA, g1f, b1f, scb1);

    const int G = 8 * (CH/64);
    for (int c = 0; c < NCH2; c++){
        k_y1mat<<<1024, 256, 0, stream>>>(z, idx2, xyzd, w1xp, scb1, t1, c*CH);
        k_gemm <<<G, 256, 0, stream>>>(w2f, t1, FF, nullptr, nullptr, statsL2);
    }
    k_finL <<<2, 256, 0, stream>>>(statsL2, g2f, b2f, scbL2);
    for (int c = 0; c < NCH2; c++){
        k_y1mat<<<1024, 256, 0, stream>>>(z, idx2, xyzd, w1xp, scb1, t1, c*CH);
        k_gemm <<<G, 256, 0, stream>>>(w2f, t1, FF, nullptr, t2, nullptr);
        k_gemm <<<G, 256, 0, stream>>>(w3f, t2, FF, scbL2, nullptr, statsL3);
    }
    k_finL <<<2, 256, 0, stream>>>(statsL3, g3f, b3f, scbL3);
    for (int c = 0; c < NCH2; c++){
        k_y1mat<<<1024, 256, 0, stream>>>(z, idx2, xyzd, w1xp, scb1, t1, c*CH);
        k_gemm <<<G, 256, 0, stream>>>(w2f, t1, FF, nullptr, t2, nullptr);
        k_gemm <<<G, 256, 0, stream>>>(w3f, t2, FF, scbL2, t1, nullptr);
        k_maxout<<<CH/KK, 256, 0, stream>>>(t1, scbL3, out, c*(CH/KK));
    }

    // diagnostics: float sentinel into out[0] on first unhealthy stage; no-op when healthy
    k_diag<<<1, 256, 0, stream>>>(ffp, w1f, featT, z, (const float*)xyzd,
                                  scb1, scbL2, scbL3, t1, out);
}